// Round 17
// baseline (69.435 us; speedup 1.0000x reference)
//
#include <hip/hip_runtime.h>
#include <stdint.h>

#define CIN   256
#define COUT  256
#define NE    64
#define RD    64
#define NTOK  2048

typedef __attribute__((ext_vector_type(8))) short bf16x8;
typedef __attribute__((ext_vector_type(4))) float f32x4;

// ---------- helpers ----------
__device__ inline unsigned short f2bf(float f) {
    uint32_t u = __float_as_uint(f);
    uint32_t r = (u + 0x7FFFu + ((u >> 16) & 1u)) >> 16;   // RNE, finite inputs
    return (unsigned short)r;
}

__device__ inline float wave_sum(float v) {
    #pragma unroll
    for (int m = 1; m < 64; m <<= 1) v += __shfl_xor(v, m, 64);
    return v;
}
__device__ inline float wave_max(float v) {
    #pragma unroll
    for (int m = 1; m < 64; m <<= 1) v = fmaxf(v, __shfl_xor(v, m, 64));
    return v;
}

__device__ inline uint32_t rotl32(uint32_t v, int d) { return (v << d) | (v >> (32 - d)); }

// Threefry-2x32, key = (0, 42), matching JAX's threefry2x32 exactly.
__device__ inline void threefry_0_42(uint32_t c0, uint32_t c1, uint32_t& o0, uint32_t& o1) {
    const uint32_t ks0 = 0u, ks1 = 42u, ks2 = 0u ^ 42u ^ 0x1BD11BDAu;
    uint32_t x0 = c0 + ks0, x1 = c1 + ks1;
#define TF_R(r) { x0 += x1; x1 = rotl32(x1, r); x1 ^= x0; }
    TF_R(13) TF_R(15) TF_R(26) TF_R(6)
    x0 += ks1; x1 += ks2 + 1u;
    TF_R(17) TF_R(29) TF_R(16) TF_R(24)
    x0 += ks2; x1 += ks0 + 2u;
    TF_R(13) TF_R(15) TF_R(26) TF_R(6)
    x0 += ks0; x1 += ks1 + 3u;
    TF_R(17) TF_R(29) TF_R(16) TF_R(24)
    x0 += ks1; x1 += ks2 + 4u;
    TF_R(13) TF_R(15) TF_R(26) TF_R(6)
    x0 += ks2; x1 += ks0 + 5u;
#undef TF_R
    o0 = x0; o1 = x1;
}

// ---------- kernel 1: fused [vq | pack_b v2] (r10-validated layout) ----------
// blocks 0..511: vq (4 tokens/block).  blocks 512..2559: pack.
// Bp v2: 2048 tiles of 4 KB, tile = ((ct*8+g)<<5) + p, p = e_local*4 + kquad.
// Tile granule qg (16B): n = qg>>3, gp = qg&7 holds k16 = gp ^ (n&7)
// -> linear global_load_lds dest + 2-way-max (free) banks on ds_read_b128.
__global__ __launch_bounds__(256) void vq_pack_kernel(
    const float* __restrict__ pw, unsigned short* __restrict__ Bp,
    const float* __restrict__ x, const float* __restrict__ mw,
    const float* __restrict__ mb, const float* __restrict__ cent,
    float* __restrict__ resp_out, float* __restrict__ commit_out)
{
    __shared__ float xs[4][CIN];
    __shared__ float cs[NE][RD + 1];
    __shared__ float ksh[4][RD];
    __shared__ float rs[4][NE];

    const int tid = threadIdx.x;

    if (blockIdx.x >= 512) {
        // ---- pack path (layout v2) ----
        int G = (blockIdx.x - 512) * 256 + tid;   // 16B-granule id, 524288 total
        int tile = G >> 8, qg = G & 255;
        int ct = tile >> 8, g = (tile >> 5) & 7, p = tile & 31;
        int e = (g << 3) + (p >> 2);
        int n = qg >> 3, gp = qg & 7;
        int k16 = gp ^ (n & 7);
        int o = (ct << 5) + n;
        int i = ((p & 3) << 6) + (k16 << 3);
        const float* s = pw + ((size_t)e << 16) + (o << 8) + i;
        float4 v0 = *(const float4*)s;
        float4 v1 = *(const float4*)(s + 4);
        ushort4 a, b;
        a.x = f2bf(v0.x); a.y = f2bf(v0.y); a.z = f2bf(v0.z); a.w = f2bf(v0.w);
        b.x = f2bf(v1.x); b.y = f2bf(v1.y); b.z = f2bf(v1.z); b.w = f2bf(v1.w);
        *(ushort4*)(Bp + ((size_t)G << 3)) = a;
        *(ushort4*)(Bp + ((size_t)G << 3) + 4) = b;
        return;
    }

    // ---- vq path (arithmetic identical to round 3) ----
    const int w  = tid >> 6;
    const int t  = tid & 63;
    const int tb = (blockIdx.x << 2) + w;

    ((float4*)xs[w])[t] = ((const float4*)(x + (size_t)tb * CIN))[t];
    #pragma unroll
    for (int j = 0; j < 4; ++j) {
        int fidx = (j << 8) + tid;
        float4 v = ((const float4*)cent)[fidx];
        int row = fidx >> 4, c0 = (fidx & 15) << 2;
        cs[row][c0] = v.x; cs[row][c0 + 1] = v.y; cs[row][c0 + 2] = v.z; cs[row][c0 + 3] = v.w;
    }
    __syncthreads();

    float kr = mb[t];
    const float4* mwr = (const float4*)(mw + (size_t)t * CIN);
    #pragma unroll 8
    for (int j = 0; j < 64; ++j) {
        float4 wv = mwr[j];
        kr += wv.x * xs[w][(j << 2)] + wv.y * xs[w][(j << 2) + 1]
            + wv.z * xs[w][(j << 2) + 2] + wv.w * xs[w][(j << 2) + 3];
    }
    ksh[w][t] = kr;
    float kk = wave_sum(kr * kr);
    __syncthreads();

    float cc = 0.f, dt = 0.f;
    #pragma unroll 8
    for (int r = 0; r < 64; ++r) {
        float cv = cs[t][r];
        cc += cv * cv;
        dt += ksh[w][r] * cv;
    }
    float d = kk + cc - 2.f * dt;

    uint32_t fidx = (uint32_t)((tb << 6) + t);
    uint32_t cnt  = fidx < 65536u ? fidx : fidx - 65536u;
    uint32_t o0, o1;
    threefry_0_42(cnt, cnt + 65536u, o0, o1);
    uint32_t bits = fidx < 65536u ? o0 : o1;
    float uf = __uint_as_float((bits >> 9) | 0x3f800000u) - 1.0f;
    uf = fmaxf(uf, 1.17549435e-38f);
    float g2 = -logf(-logf(uf));

    float sv = g2 - d;                 // TAU = 1
    float mx = wave_max(sv);
    float pz = expf(sv - mx);
    float ps = wave_sum(pz);
    float rv = pz / ps;
    resp_out[(tb << 6) + t] = rv;
    rs[w][t] = rv;
    __syncthreads();

    float q = 0.f;
    #pragma unroll 8
    for (int e2 = 0; e2 < 64; ++e2) q += rs[w][e2] * cs[e2][t];
    float df = kr - q;
    float sq = wave_sum(df * df);
    if (t == 0) commit_out[tb] = sq;
}

// ---------- kernel 2: fused [MoE GEMM v3 (M64/wave) | loss partials] ----------
// blocks 0..511: r10's validated M256xN32 gemm (4 waves x M64xN32; af = 32
// named bf16x8 = 128 VGPR; 4-slot x 4KB ring, BK=64, 32 phases, counted
// vmcnt(2)).  blocks 512..543: loss partials.
// KEY CHANGE vs r10: amdgpu_waves_per_eu(2,2) pins the allocator at 2
// waves/EU -> no occupancy incentive below 256 VGPRs -> the ~200-reg demand
// compiles spill-free (r10/r11/r12 failed on allocator sandbagging to
// 84-128 VGPR, not on arithmetic).
struct GemmRegs {
    f32x4 P00, P01, P10, P11, P20, P21, P30, P31;
    f32x4 O00, O01, O10, O11, O20, O21, O30, O31;
};

template<int T>
__device__ __attribute__((always_inline)) inline void stage4(
    const char* bsrc, char* Bb, int w, int lane)
{
    __builtin_amdgcn_global_load_lds(
        (const __attribute__((address_space(1))) unsigned int*)
            (bsrc + ((size_t)T << 12) + (w << 10) + (lane << 4)),
        (__attribute__((address_space(3))) unsigned int*)
            (Bb + ((T & 3) << 12) + (w << 10)), 16, 0, 0);
}

template<int T>
__device__ __attribute__((always_inline)) inline void phase(
    const char* bsrc, char* Bb,
    const bf16x8& a00, const bf16x8& a10, const bf16x8& a20, const bf16x8& a30,
    const bf16x8& a01, const bf16x8& a11, const bf16x8& a21, const bf16x8& a31,
    GemmRegs& R, const float (*rsh)[8], int w, int lane, int lo, int kq)
{
    // counted wait: stage T landed; stages T+1,T+2 stay in flight (1 load/stage)
    if constexpr (T <= 29)      asm volatile("s_waitcnt vmcnt(2)" ::: "memory");
    else if constexpr (T == 30) asm volatile("s_waitcnt vmcnt(1)" ::: "memory");
    else                        asm volatile("s_waitcnt vmcnt(0)" ::: "memory");
    asm volatile("s_barrier" ::: "memory");   // all waves confirmed stage T

    // refill slot (T+3)&3 == (T-1)&3: reads finished in phase T-1 before this
    // barrier in every wave's program order -> write-after-read safe.
    if constexpr (T + 3 < 32) stage4<T + 3>(bsrc, Bb, w, lane);

    const char* bt = Bb + ((T & 3) << 12);
    bf16x8 b00, b10, b01, b11;
    { int n = lo;      b00 = *(const bf16x8*)(bt + (n << 7) + (((kq)     ^ (n & 7)) << 4)); }
    { int n = 16 + lo; b10 = *(const bf16x8*)(bt + (n << 7) + (((kq)     ^ (n & 7)) << 4)); }
    { int n = lo;      b01 = *(const bf16x8*)(bt + (n << 7) + (((4 + kq) ^ (n & 7)) << 4)); }
    { int n = 16 + lo; b11 = *(const bf16x8*)(bt + (n << 7) + (((4 + kq) ^ (n & 7)) << 4)); }

    // kc = 0 (k-chunk 2(T&3))
    R.P00 = __builtin_amdgcn_mfma_f32_16x16x32_bf16(a00, b00, R.P00, 0, 0, 0);
    R.P01 = __builtin_amdgcn_mfma_f32_16x16x32_bf16(a00, b10, R.P01, 0, 0, 0);
    R.P10 = __builtin_amdgcn_mfma_f32_16x16x32_bf16(a10, b00, R.P10, 0, 0, 0);
    R.P11 = __builtin_amdgcn_mfma_f32_16x16x32_bf16(a10, b10, R.P11, 0, 0, 0);
    R.P20 = __builtin_amdgcn_mfma_f32_16x16x32_bf16(a20, b00, R.P20, 0, 0, 0);
    R.P21 = __builtin_amdgcn_mfma_f32_16x16x32_bf16(a20, b10, R.P21, 0, 0, 0);
    R.P30 = __builtin_amdgcn_mfma_f32_16x16x32_bf16(a30, b00, R.P30, 0, 0, 0);
    R.P31 = __builtin_amdgcn_mfma_f32_16x16x32_bf16(a30, b10, R.P31, 0, 0, 0);
    // kc = 1 (k-chunk 2(T&3)+1)
    R.P00 = __builtin_amdgcn_mfma_f32_16x16x32_bf16(a01, b01, R.P00, 0, 0, 0);
    R.P01 = __builtin_amdgcn_mfma_f32_16x16x32_bf16(a01, b11, R.P01, 0, 0, 0);
    R.P10 = __builtin_amdgcn_mfma_f32_16x16x32_bf16(a11, b01, R.P10, 0, 0, 0);
    R.P11 = __builtin_amdgcn_mfma_f32_16x16x32_bf16(a11, b11, R.P11, 0, 0, 0);
    R.P20 = __builtin_amdgcn_mfma_f32_16x16x32_bf16(a21, b01, R.P20, 0, 0, 0);
    R.P21 = __builtin_amdgcn_mfma_f32_16x16x32_bf16(a21, b11, R.P21, 0, 0, 0);
    R.P30 = __builtin_amdgcn_mfma_f32_16x16x32_bf16(a31, b01, R.P30, 0, 0, 0);
    R.P31 = __builtin_amdgcn_mfma_f32_16x16x32_bf16(a31, b11, R.P31, 0, 0, 0);

    if constexpr ((T & 3) == 3) {   // expert (T>>2) done: O += resp*P; P = 0
        constexpr int el = T >> 2;
        const int rb = (w << 6) + (kq << 2);
        const f32x4 z = {};
#define EPI(MI) { \
        float r0_ = rsh[rb + (MI << 4) + 0][el], r1_ = rsh[rb + (MI << 4) + 1][el]; \
        float r2_ = rsh[rb + (MI << 4) + 2][el], r3_ = rsh[rb + (MI << 4) + 3][el]; \
        R.O##MI##0[0] += r0_ * R.P##MI##0[0]; R.O##MI##0[1] += r1_ * R.P##MI##0[1]; \
        R.O##MI##0[2] += r2_ * R.P##MI##0[2]; R.O##MI##0[3] += r3_ * R.P##MI##0[3]; \
        R.O##MI##1[0] += r0_ * R.P##MI##1[0]; R.O##MI##1[1] += r1_ * R.P##MI##1[1]; \
        R.O##MI##1[2] += r2_ * R.P##MI##1[2]; R.O##MI##1[3] += r3_ * R.P##MI##1[3]; \
        R.P##MI##0 = z; R.P##MI##1 = z; }
        EPI(0) EPI(1) EPI(2) EPI(3)
#undef EPI
    }
}

__global__ __launch_bounds__(256)
__attribute__((amdgpu_waves_per_eu(2, 2)))
void gemm_loss_kernel(
    const float* __restrict__ x, const float* __restrict__ resp,
    const unsigned short* __restrict__ Bp, float* __restrict__ partial,
    const float* __restrict__ commit_part, float* __restrict__ imp_p,
    float* __restrict__ cm_p)
{
    __shared__ char Bb[16384];        // 4 ring slots x 4 KB
    __shared__ float rsh[256][8];     // resp tile [row][e_local]

    const int tid  = threadIdx.x;

    if (blockIdx.x >= 512) {
        // ---- loss partials path (aliases Bb for its 1 KB scratch) ----
        float (*part)[64] = (float (*)[64])Bb;
        const int b = blockIdx.x - 512;
        const int e = tid & 63, grp = tid >> 6;
        float s = 0.f;
        #pragma unroll
        for (int j = 0; j < 16; ++j)
            s += resp[(size_t)((b << 6) + (grp << 4) + j) * 64 + e];
        part[grp][e] = s;
        __syncthreads();
        if (tid < 64) {
            float v = part[0][tid] + part[1][tid] + part[2][tid] + part[3][tid];
            imp_p[(b << 6) + tid] = v;
            float cm = commit_part[(b << 6) + tid];
            cm = wave_sum(cm);
            if (tid == 0) cm_p[b] = cm;
        }
        return;
    }

    // ---- gemm path (r10 body, verbatim) ----
    const int lane = tid & 63;
    const int w    = tid >> 6;        // 4 waves, 64 rows each
    const int lo   = lane & 15, kq = lane >> 4;
    const int bid  = blockIdx.x;
    const int g    = bid & 7, ct = (bid >> 3) & 7, mt = bid >> 6;
    const int m0   = mt << 8;

    // ---- resp tile: 256 rows x 8 experts, two float4 per thread ----
    {
        float4 r0 = *(const float4*)(resp + ((size_t)(m0 + tid) << 6) + (g << 3));
        float4 r1 = *(const float4*)(resp + ((size_t)(m0 + tid) << 6) + (g << 3) + 4);
        *(float4*)(&rsh[tid][0]) = r0;
        *(float4*)(&rsh[tid][4]) = r1;
    }

    // ---- A frags: 32 named registers af{mi}{kc}, rows = m0+w*64+mi*16+lo ----
    bf16x8 af00, af01, af02, af03, af04, af05, af06, af07;
    bf16x8 af10, af11, af12, af13, af14, af15, af16, af17;
    bf16x8 af20, af21, af22, af23, af24, af25, af26, af27;
    bf16x8 af30, af31, af32, af33, af34, af35, af36, af37;
    {
        const float* xb = x + ((size_t)(m0 + (w << 6) + lo) << 8) + (kq << 3);
#define LAF(MI, KC) { \
        const float* s_ = xb + (MI * 4096) + (KC * 32); \
        float4 v0_ = *(const float4*)s_; \
        float4 v1_ = *(const float4*)(s_ + 4); \
        bf16x8 bv_; \
        bv_[0] = (short)f2bf(v0_.x); bv_[1] = (short)f2bf(v0_.y); \
        bv_[2] = (short)f2bf(v0_.z); bv_[3] = (short)f2bf(v0_.w); \
        bv_[4] = (short)f2bf(v1_.x); bv_[5] = (short)f2bf(v1_.y); \
        bv_[6] = (short)f2bf(v1_.z); bv_[7] = (short)f2bf(v1_.w); \
        af##MI##KC = bv_; }
        LAF(0,0) LAF(0,1) LAF(0,2) LAF(0,3) LAF(0,4) LAF(0,5) LAF(0,6) LAF(0,7)
        LAF(1,0) LAF(1,1) LAF(1,2) LAF(1,3) LAF(1,4) LAF(1,5) LAF(1,6) LAF(1,7)
        LAF(2,0) LAF(2,1) LAF(2,2) LAF(2,3) LAF(2,4) LAF(2,5) LAF(2,6) LAF(2,7)
        LAF(3,0) LAF(3,1) LAF(3,2) LAF(3,3) LAF(3,4) LAF(3,5) LAF(3,6) LAF(3,7)
#undef LAF
    }

    const char* bsrc = (const char*)Bp + ((size_t)((ct << 3) + g) << 17);

    // drain: A/rsh vmem consumed (vmcnt count starts clean), rsh writes done
    asm volatile("s_waitcnt vmcnt(0)" ::: "memory");
    asm volatile("s_waitcnt lgkmcnt(0)" ::: "memory");

    // prologue: prefetch stages 0..2 (1 load per wave per stage)
    stage4<0>(bsrc, Bb, w, lane);
    stage4<1>(bsrc, Bb, w, lane);
    stage4<2>(bsrc, Bb, w, lane);

    GemmRegs R = {};

#define CPH(T, KA, KB) phase<T>(bsrc, Bb, \
        af0##KA, af1##KA, af2##KA, af3##KA, \
        af0##KB, af1##KB, af2##KB, af3##KB, R, rsh, w, lane, lo, kq);
    CPH( 0,0,1) CPH( 1,2,3) CPH( 2,4,5) CPH( 3,6,7)
    CPH( 4,0,1) CPH( 5,2,3) CPH( 6,4,5) CPH( 7,6,7)
    CPH( 8,0,1) CPH( 9,2,3) CPH(10,4,5) CPH(11,6,7)
    CPH(12,0,1) CPH(13,2,3) CPH(14,4,5) CPH(15,6,7)
    CPH(16,0,1) CPH(17,2,3) CPH(18,4,5) CPH(19,6,7)
    CPH(20,0,1) CPH(21,2,3) CPH(22,4,5) CPH(23,6,7)
    CPH(24,0,1) CPH(25,2,3) CPH(26,4,5) CPH(27,6,7)
    CPH(28,0,1) CPH(29,2,3) CPH(30,4,5) CPH(31,6,7)
#undef CPH

    // ---- write partial [g][2048][256] ----
    float* pout = partial + ((size_t)g << 19)
                + ((size_t)(m0 + (w << 6) + (kq << 2)) << 8) + (ct << 5) + lo;
#define STO(MI) { \
        float* p0_ = pout + (((MI << 4) + 0) << 8); p0_[0] = R.O##MI##0[0]; p0_[16] = R.O##MI##1[0]; \
        float* p1_ = pout + (((MI << 4) + 1) << 8); p1_[0] = R.O##MI##0[1]; p1_[16] = R.O##MI##1[1]; \
        float* p2_ = pout + (((MI << 4) + 2) << 8); p2_[0] = R.O##MI##0[2]; p2_[16] = R.O##MI##1[2]; \
        float* p3_ = pout + (((MI << 4) + 3) << 8); p3_[0] = R.O##MI##0[3]; p3_[16] = R.O##MI##1[3]; }
    STO(0) STO(1) STO(2) STO(3)
#undef STO
}

// ---------- kernel 3: fused [reduce | final loss] ----------
// blocks 0..511: split-partial reduce + bias.  block 512: loss scalar
// (reads imp_p/cm_p written by the PREVIOUS launch — kernel-boundary
// ordering, no fences needed).
__global__ __launch_bounds__(256) void reduce_final_kernel(
    const float* __restrict__ partial, const float* __restrict__ bias,
    float* __restrict__ out, const float* __restrict__ imp_p,
    const float* __restrict__ cm_p, float* __restrict__ loss_out)
{
    const int t = threadIdx.x;

    if (blockIdx.x < 512) {
        int idx = blockIdx.x * 256 + t;   // float4 id, < 131072
        float4 s = ((const float4*)bias)[idx & 63];
        #pragma unroll
        for (int g = 0; g < 8; ++g) {
            float4 v = ((const float4*)partial)[((size_t)g << 17) + idx];
            s.x += v.x; s.y += v.y; s.z += v.z; s.w += v.w;
        }
        ((float4*)out)[idx] = s;
        return;
    }

    // ---- final loss (block 512, first wave) ----
    if (t < 64) {
        float imp = 0.f;
        #pragma unroll
        for (int b = 0; b < 32; ++b) imp += imp_p[(b << 6) + t];
        float ct = (t < 32) ? cm_p[t] : 0.f;
        ct = wave_sum(ct);
        float tot  = wave_sum(imp);
        float mean = tot * (1.0f / 64.f);
        float dv   = imp - mean;
        float var  = wave_sum(dv * dv) * (1.0f / 63.f);
        if (t == 0) {
            float mse = ct * (1.0f / (float)(NTOK * RD));
            float imp_loss = sqrtf(var) / mean;
            // commitment and kmeans losses are numerically identical forward
            loss_out[0] = (0.25f + 1.0f) * mse + 30.0f * imp_loss;
        }
    }
}

extern "C" void kernel_launch(void* const* d_in, const int* in_sizes, int n_in,
                              void* d_out, int out_size, void* d_ws, size_t ws_size,
                              hipStream_t stream)
{
    const float* x     = (const float*)d_in[0];
    const float* map_w = (const float*)d_in[1];
    const float* map_b = (const float*)d_in[2];
    const float* cent  = (const float*)d_in[3];
    const float* pw_w  = (const float*)d_in[4];
    const float* pw_B  = (const float*)d_in[5];
    float* out = (float*)d_out;

    char* ws = (char*)d_ws;
    float* resp        = (float*)ws;                          // 512 KB
    float* commit      = (float*)(ws + 524288);               // 8 KB
    float* imp_p       = (float*)(ws + 540672);               // 8 KB
    float* cm_p        = (float*)(ws + 557056);               // 128 B
    unsigned short* Bp = (unsigned short*)(ws + (1u << 20));  // 8 MB packed B
    float* partial     = (float*)(ws + (10u << 20));          // 8 * 2 MB = 16 MB

    vq_pack_kernel<<<2560, 256, 0, stream>>>(pw_w, Bp, x, map_w, map_b, cent,
                                             resp, commit);
    gemm_loss_kernel<<<544, 256, 0, stream>>>(x, resp, Bp, partial,
                                              commit, imp_p, cm_p);
    reduce_final_kernel<<<513, 256, 0, stream>>>(partial, pw_B, out,
                                                 imp_p, cm_p, out + NTOK * COUT);
}

// Round 18
// 54.847 us; speedup vs baseline: 1.2660x; 1.2660x over previous
//
#include <hip/hip_runtime.h>
#include <stdint.h>

#define CIN   256
#define COUT  256
#define NE    64
#define RD    64
#define NTOK  2048

typedef __attribute__((ext_vector_type(8))) short bf16x8;
typedef __attribute__((ext_vector_type(4))) float f32x4;

// ---------- helpers ----------
__device__ inline unsigned short f2bf(float f) {
    uint32_t u = __float_as_uint(f);
    uint32_t r = (u + 0x7FFFu + ((u >> 16) & 1u)) >> 16;   // RNE, finite inputs
    return (unsigned short)r;
}

__device__ inline float wave_sum(float v) {
    #pragma unroll
    for (int m = 1; m < 64; m <<= 1) v += __shfl_xor(v, m, 64);
    return v;
}
__device__ inline float wave_max(float v) {
    #pragma unroll
    for (int m = 1; m < 64; m <<= 1) v = fmaxf(v, __shfl_xor(v, m, 64));
    return v;
}

__device__ inline uint32_t rotl32(uint32_t v, int d) { return (v << d) | (v >> (32 - d)); }

// Threefry-2x32, key = (0, 42), matching JAX's threefry2x32 exactly.
__device__ inline void threefry_0_42(uint32_t c0, uint32_t c1, uint32_t& o0, uint32_t& o1) {
    const uint32_t ks0 = 0u, ks1 = 42u, ks2 = 0u ^ 42u ^ 0x1BD11BDAu;
    uint32_t x0 = c0 + ks0, x1 = c1 + ks1;
#define TF_R(r) { x0 += x1; x1 = rotl32(x1, r); x1 ^= x0; }
    TF_R(13) TF_R(15) TF_R(26) TF_R(6)
    x0 += ks1; x1 += ks2 + 1u;
    TF_R(17) TF_R(29) TF_R(16) TF_R(24)
    x0 += ks2; x1 += ks0 + 2u;
    TF_R(13) TF_R(15) TF_R(26) TF_R(6)
    x0 += ks0; x1 += ks1 + 3u;
    TF_R(17) TF_R(29) TF_R(16) TF_R(24)
    x0 += ks1; x1 += ks2 + 4u;
    TF_R(13) TF_R(15) TF_R(26) TF_R(6)
    x0 += ks2; x1 += ks0 + 5u;
#undef TF_R
    o0 = x0; o1 = x1;
}

// ---------- kernel 1: fused [vq | pack_b] (r8 v1 layout, byte-identical) ----------
// blocks 0..511: vq (4 tokens/block).  blocks 512..2559: pack.
// Bp layout: 2048 tiles of 4 KB, tile = (ct*8+g)*64 + p where p = e_local*8+kc.
// Tile granule qg (16B): n = qg>>2, gp = qg&3 holds k16 = gp ^ ((n>>1)&3)
// -> linear global_load_lds dest + conflict-free ds_read_b128.
__global__ __launch_bounds__(256) void vq_pack_kernel(
    const float* __restrict__ pw, unsigned short* __restrict__ Bp,
    const float* __restrict__ x, const float* __restrict__ mw,
    const float* __restrict__ mb, const float* __restrict__ cent,
    float* __restrict__ resp_out, float* __restrict__ commit_out)
{
    __shared__ float xs[4][CIN];
    __shared__ float cs[NE][RD + 1];
    __shared__ float ksh[4][RD];
    __shared__ float rs[4][NE];

    const int tid = threadIdx.x;

    if (blockIdx.x >= 512) {
        // ---- pack path ----
        int G = (blockIdx.x - 512) * 256 + tid;   // 16B-granule id, 524288 total
        int tile = G >> 8, qg = G & 255;
        int ct = tile >> 9, g = (tile >> 6) & 7, p = tile & 63;
        int e = (g << 3) + (p >> 3), kc = p & 7;
        int n = qg >> 2, gp = qg & 3;
        int k16 = gp ^ ((n >> 1) & 3);
        int o = (ct << 6) + n;
        const float* s = pw + ((size_t)e << 16) + (o << 8) + (kc << 5) + (k16 << 3);
        float4 v0 = *(const float4*)s;
        float4 v1 = *(const float4*)(s + 4);
        ushort4 a, b;
        a.x = f2bf(v0.x); a.y = f2bf(v0.y); a.z = f2bf(v0.z); a.w = f2bf(v0.w);
        b.x = f2bf(v1.x); b.y = f2bf(v1.y); b.z = f2bf(v1.z); b.w = f2bf(v1.w);
        *(ushort4*)(Bp + ((size_t)G << 3)) = a;
        *(ushort4*)(Bp + ((size_t)G << 3) + 4) = b;
        return;
    }

    // ---- vq path (arithmetic identical to round 3) ----
    const int w  = tid >> 6;
    const int t  = tid & 63;
    const int tb = (blockIdx.x << 2) + w;

    ((float4*)xs[w])[t] = ((const float4*)(x + (size_t)tb * CIN))[t];
    #pragma unroll
    for (int j = 0; j < 4; ++j) {
        int fidx = (j << 8) + tid;
        float4 v = ((const float4*)cent)[fidx];
        int row = fidx >> 4, c0 = (fidx & 15) << 2;
        cs[row][c0] = v.x; cs[row][c0 + 1] = v.y; cs[row][c0 + 2] = v.z; cs[row][c0 + 3] = v.w;
    }
    __syncthreads();

    float kr = mb[t];
    const float4* mwr = (const float4*)(mw + (size_t)t * CIN);
    #pragma unroll 8
    for (int j = 0; j < 64; ++j) {
        float4 wv = mwr[j];
        kr += wv.x * xs[w][(j << 2)] + wv.y * xs[w][(j << 2) + 1]
            + wv.z * xs[w][(j << 2) + 2] + wv.w * xs[w][(j << 2) + 3];
    }
    ksh[w][t] = kr;
    float kk = wave_sum(kr * kr);
    __syncthreads();

    float cc = 0.f, dt = 0.f;
    #pragma unroll 8
    for (int r = 0; r < 64; ++r) {
        float cv = cs[t][r];
        cc += cv * cv;
        dt += ksh[w][r] * cv;
    }
    float d = kk + cc - 2.f * dt;

    uint32_t fidx = (uint32_t)((tb << 6) + t);
    uint32_t cnt  = fidx < 65536u ? fidx : fidx - 65536u;
    uint32_t o0, o1;
    threefry_0_42(cnt, cnt + 65536u, o0, o1);
    uint32_t bits = fidx < 65536u ? o0 : o1;
    float uf = __uint_as_float((bits >> 9) | 0x3f800000u) - 1.0f;
    uf = fmaxf(uf, 1.17549435e-38f);
    float g2 = -logf(-logf(uf));

    float sv = g2 - d;                 // TAU = 1
    float mx = wave_max(sv);
    float pz = expf(sv - mx);
    float ps = wave_sum(pz);
    float rv = pz / ps;
    resp_out[(tb << 6) + t] = rv;
    rs[w][t] = rv;
    __syncthreads();

    float q = 0.f;
    #pragma unroll 8
    for (int e2 = 0; e2 < 64; ++e2) q += rs[w][e2] * cs[e2][t];
    float df = kr - q;
    float sq = wave_sum(df * df);
    if (t == 0) commit_out[tb] = sq;
}

// ---------- kernel 2: fused [MoE GEMM | loss partials] ----------
// blocks 0..511: r8 gemm body with 3-slot ring, counted vmcnt(4)
// (r14 configuration — best measured, 54.85 us total).
// blocks 512..543: loss partials.
struct GemmRegs {
    f32x4 P00, P01, P02, P03, P10, P11, P12, P13;
    f32x4 O00, O01, O02, O03, O10, O11, O12, O13;
};

template<int T>
__device__ __attribute__((always_inline)) inline void stage16(
    const char* bsrc, char* Bb, int w, int lane)
{
    const char* src = bsrc + ((size_t)T << 14) + (w << 12) + (lane << 4);
    char* dst = Bb + (T % 3) * 16384 + (w << 12);
    #pragma unroll
    for (int i = 0; i < 4; ++i)
        __builtin_amdgcn_global_load_lds(
            (const __attribute__((address_space(1))) unsigned int*)(src + (i << 10)),
            (__attribute__((address_space(3))) unsigned int*)(dst + (i << 10)), 16, 0, 0);
}

template<int T>
__device__ __attribute__((always_inline)) inline void phase(
    const char* bsrc, char* Bb,
    const bf16x8& a00, const bf16x8& a01, const bf16x8& a02, const bf16x8& a03,
    const bf16x8& a10, const bf16x8& a11, const bf16x8& a12, const bf16x8& a13,
    GemmRegs& R, const float (*rsh)[8], int w, int lane, int lo, int kq)
{
    // counted wait: stage T landed; stage T+1 (4 loads) stays in flight
    if constexpr (T <= 14) asm volatile("s_waitcnt vmcnt(4)" ::: "memory");
    else                   asm volatile("s_waitcnt vmcnt(0)" ::: "memory");
    asm volatile("s_barrier" ::: "memory");   // all waves confirmed stage T

    // refill slot (T+2)%3 == (T-1)%3: its reads finished in phase T-1,
    // which precedes this barrier in every wave's program order -> safe.
    if constexpr (T + 2 < 16) stage16<T + 2>(bsrc, Bb, w, lane);

    const char* bt = Bb + (T % 3) * 16384;
    #pragma unroll
    for (int kc = 0; kc < 4; ++kc) {
        const char* bk = bt + (kc << 12);
        bf16x8 b0, b1, b2, b3;
        { int n = lo;      b0 = *(const bf16x8*)(bk + (n << 6) + ((kq ^ ((n >> 1) & 3)) << 4)); }
        { int n = 16 + lo; b1 = *(const bf16x8*)(bk + (n << 6) + ((kq ^ ((n >> 1) & 3)) << 4)); }
        { int n = 32 + lo; b2 = *(const bf16x8*)(bk + (n << 6) + ((kq ^ ((n >> 1) & 3)) << 4)); }
        { int n = 48 + lo; b3 = *(const bf16x8*)(bk + (n << 6) + ((kq ^ ((n >> 1) & 3)) << 4)); }
        const bf16x8& am0 = (kc == 0) ? a00 : (kc == 1) ? a01 : (kc == 2) ? a02 : a03;
        const bf16x8& am1 = (kc == 0) ? a10 : (kc == 1) ? a11 : (kc == 2) ? a12 : a13;
        R.P00 = __builtin_amdgcn_mfma_f32_16x16x32_bf16(am0, b0, R.P00, 0, 0, 0);
        R.P01 = __builtin_amdgcn_mfma_f32_16x16x32_bf16(am0, b1, R.P01, 0, 0, 0);
        R.P02 = __builtin_amdgcn_mfma_f32_16x16x32_bf16(am0, b2, R.P02, 0, 0, 0);
        R.P03 = __builtin_amdgcn_mfma_f32_16x16x32_bf16(am0, b3, R.P03, 0, 0, 0);
        R.P10 = __builtin_amdgcn_mfma_f32_16x16x32_bf16(am1, b0, R.P10, 0, 0, 0);
        R.P11 = __builtin_amdgcn_mfma_f32_16x16x32_bf16(am1, b1, R.P11, 0, 0, 0);
        R.P12 = __builtin_amdgcn_mfma_f32_16x16x32_bf16(am1, b2, R.P12, 0, 0, 0);
        R.P13 = __builtin_amdgcn_mfma_f32_16x16x32_bf16(am1, b3, R.P13, 0, 0, 0);
    }

    if constexpr (T & 1) {   // expert (T>>1) done: O += resp * P; P = 0
        constexpr int el = T >> 1;
        const int rb = (w << 5) + (kq << 2);
        float r00 = rsh[rb +  0][el], r01 = rsh[rb +  1][el];
        float r02 = rsh[rb +  2][el], r03 = rsh[rb +  3][el];
        float r10 = rsh[rb + 16][el], r11 = rsh[rb + 17][el];
        float r12 = rsh[rb + 18][el], r13 = rsh[rb + 19][el];
        const f32x4 z = {};
        R.O00[0] += r00 * R.P00[0]; R.O00[1] += r01 * R.P00[1]; R.O00[2] += r02 * R.P00[2]; R.O00[3] += r03 * R.P00[3];
        R.O01[0] += r00 * R.P01[0]; R.O01[1] += r01 * R.P01[1]; R.O01[2] += r02 * R.P01[2]; R.O01[3] += r03 * R.P01[3];
        R.O02[0] += r00 * R.P02[0]; R.O02[1] += r01 * R.P02[1]; R.O02[2] += r02 * R.P02[2]; R.O02[3] += r03 * R.P02[3];
        R.O03[0] += r00 * R.P03[0]; R.O03[1] += r01 * R.P03[1]; R.O03[2] += r02 * R.P03[2]; R.O03[3] += r03 * R.P03[3];
        R.O10[0] += r10 * R.P10[0]; R.O10[1] += r11 * R.P10[1]; R.O10[2] += r12 * R.P10[2]; R.O10[3] += r13 * R.P10[3];
        R.O11[0] += r10 * R.P11[0]; R.O11[1] += r11 * R.P11[1]; R.O11[2] += r12 * R.P11[2]; R.O11[3] += r13 * R.P11[3];
        R.O12[0] += r10 * R.P12[0]; R.O12[1] += r11 * R.P12[1]; R.O12[2] += r12 * R.P12[2]; R.O12[3] += r13 * R.P12[3];
        R.O13[0] += r10 * R.P13[0]; R.O13[1] += r11 * R.P13[1]; R.O13[2] += r12 * R.P13[2]; R.O13[3] += r13 * R.P13[3];
        R.P00 = z; R.P01 = z; R.P02 = z; R.P03 = z;
        R.P10 = z; R.P11 = z; R.P12 = z; R.P13 = z;
    }
}

#define LOAD_AF(name, base, idx) { \
    const float* s_ = (base) + ((idx) << 5); \
    float4 v0_ = *(const float4*)s_; \
    float4 v1_ = *(const float4*)(s_ + 4); \
    bf16x8 bv_; \
    bv_[0] = (short)f2bf(v0_.x); bv_[1] = (short)f2bf(v0_.y); \
    bv_[2] = (short)f2bf(v0_.z); bv_[3] = (short)f2bf(v0_.w); \
    bv_[4] = (short)f2bf(v1_.x); bv_[5] = (short)f2bf(v1_.y); \
    bv_[6] = (short)f2bf(v1_.z); bv_[7] = (short)f2bf(v1_.w); \
    name = bv_; }

__global__ __launch_bounds__(256, 2) void gemm_loss_kernel(
    const float* __restrict__ x, const float* __restrict__ resp,
    const unsigned short* __restrict__ Bp, float* __restrict__ partial,
    const float* __restrict__ commit_part, float* __restrict__ imp_p,
    float* __restrict__ cm_p)
{
    __shared__ char Bb[49152];        // 3 ring slots x 16 KB
    __shared__ float rsh[128][8];     // resp tile [row][e_local]

    const int tid  = threadIdx.x;

    if (blockIdx.x >= 512) {
        // ---- loss partials path (aliases Bb for its 1 KB scratch) ----
        float (*part)[64] = (float (*)[64])Bb;
        const int b = blockIdx.x - 512;
        const int e = tid & 63, grp = tid >> 6;
        float s = 0.f;
        #pragma unroll
        for (int j = 0; j < 16; ++j)
            s += resp[(size_t)((b << 6) + (grp << 4) + j) * 64 + e];
        part[grp][e] = s;
        __syncthreads();
        if (tid < 64) {
            float v = part[0][tid] + part[1][tid] + part[2][tid] + part[3][tid];
            imp_p[(b << 6) + tid] = v;
            float cm = commit_part[(b << 6) + tid];
            cm = wave_sum(cm);
            if (tid == 0) cm_p[b] = cm;
        }
        return;
    }

    // ---- gemm path (r8 body, 3-slot ring) ----
    const int lane = tid & 63;
    const int w    = tid >> 6;        // 4 waves, 32 rows each
    const int lo   = lane & 15, kq = lane >> 4;
    const int bid  = blockIdx.x;
    const int g    = bid & 7, ct = (bid >> 3) & 3, mt = bid >> 5;
    const int m0   = mt << 7;

    // ---- resp tile: 128 rows x 8 experts, one float4 per thread ----
    {
        int idx = tid << 2;                // 0..1020
        int row = idx >> 3, e0 = idx & 7;  // e0 in {0,4}
        float4 rv = *(const float4*)(resp + ((size_t)(m0 + row) << 6) + (g << 3) + e0);
        *(float4*)(&rsh[row][e0]) = rv;
    }

    // ---- A frags: 16 named registers, rows m0+w*32+lo (mi0) / +16 (mi1) ----
    bf16x8 af00, af01, af02, af03, af04, af05, af06, af07;
    bf16x8 af10, af11, af12, af13, af14, af15, af16, af17;
    {
        const float* xb0 = x + ((size_t)(m0 + (w << 5) + lo) << 8) + (kq << 3);
        const float* xb1 = xb0 + (16 << 8);
        LOAD_AF(af00, xb0, 0) LOAD_AF(af01, xb0, 1) LOAD_AF(af02, xb0, 2) LOAD_AF(af03, xb0, 3)
        LOAD_AF(af04, xb0, 4) LOAD_AF(af05, xb0, 5) LOAD_AF(af06, xb0, 6) LOAD_AF(af07, xb0, 7)
        LOAD_AF(af10, xb1, 0) LOAD_AF(af11, xb1, 1) LOAD_AF(af12, xb1, 2) LOAD_AF(af13, xb1, 3)
        LOAD_AF(af14, xb1, 4) LOAD_AF(af15, xb1, 5) LOAD_AF(af16, xb1, 6) LOAD_AF(af17, xb1, 7)
    }

    const char* bsrc = (const char*)Bp + ((size_t)((ct << 3) + g) << 18);

    // drain: A/rsh vmem consumed (vmcnt count starts clean), rsh writes done
    asm volatile("s_waitcnt vmcnt(0)" ::: "memory");
    asm volatile("s_waitcnt lgkmcnt(0)" ::: "memory");

    // prologue: prefetch stages 0,1 (4 loads per wave per stage)
    stage16<0>(bsrc, Bb, w, lane);
    stage16<1>(bsrc, Bb, w, lane);

    GemmRegs R = {};

    phase< 0>(bsrc, Bb, af00, af01, af02, af03, af10, af11, af12, af13, R, rsh, w, lane, lo, kq);
    phase< 1>(bsrc, Bb, af04, af05, af06, af07, af14, af15, af16, af17, R, rsh, w, lane, lo, kq);
    phase< 2>(bsrc, Bb, af00, af01, af02, af03, af10, af11, af12, af13, R, rsh, w, lane, lo, kq);
    phase< 3>(bsrc, Bb, af04, af05, af06, af07, af14, af15, af16, af17, R, rsh, w, lane, lo, kq);
    phase< 4>(bsrc, Bb, af00, af01, af02, af03, af10, af11, af12, af13, R, rsh, w, lane, lo, kq);
    phase< 5>(bsrc, Bb, af04, af05, af06, af07, af14, af15, af16, af17, R, rsh, w, lane, lo, kq);
    phase< 6>(bsrc, Bb, af00, af01, af02, af03, af10, af11, af12, af13, R, rsh, w, lane, lo, kq);
    phase< 7>(bsrc, Bb, af04, af05, af06, af07, af14, af15, af16, af17, R, rsh, w, lane, lo, kq);
    phase< 8>(bsrc, Bb, af00, af01, af02, af03, af10, af11, af12, af13, R, rsh, w, lane, lo, kq);
    phase< 9>(bsrc, Bb, af04, af05, af06, af07, af14, af15, af16, af17, R, rsh, w, lane, lo, kq);
    phase<10>(bsrc, Bb, af00, af01, af02, af03, af10, af11, af12, af13, R, rsh, w, lane, lo, kq);
    phase<11>(bsrc, Bb, af04, af05, af06, af07, af14, af15, af16, af17, R, rsh, w, lane, lo, kq);
    phase<12>(bsrc, Bb, af00, af01, af02, af03, af10, af11, af12, af13, R, rsh, w, lane, lo, kq);
    phase<13>(bsrc, Bb, af04, af05, af06, af07, af14, af15, af16, af17, R, rsh, w, lane, lo, kq);
    phase<14>(bsrc, Bb, af00, af01, af02, af03, af10, af11, af12, af13, R, rsh, w, lane, lo, kq);
    phase<15>(bsrc, Bb, af04, af05, af06, af07, af14, af15, af16, af17, R, rsh, w, lane, lo, kq);

    // ---- write partial [g][2048][256] ----
    float* pout = partial + ((size_t)g << 19)
                + ((size_t)(m0 + (w << 5) + (kq << 2)) << 8) + (ct << 6) + lo;
    {
        float* pr;
        pr = pout;                  pr[0] = R.O00[0]; pr[16] = R.O01[0]; pr[32] = R.O02[0]; pr[48] = R.O03[0];
        pr = pout + 256;            pr[0] = R.O00[1]; pr[16] = R.O01[1]; pr[32] = R.O02[1]; pr[48] = R.O03[1];
        pr = pout + 512;            pr[0] = R.O00[2]; pr[16] = R.O01[2]; pr[32] = R.O02[2]; pr[48] = R.O03[2];
        pr = pout + 768;            pr[0] = R.O00[3]; pr[16] = R.O01[3]; pr[32] = R.O02[3]; pr[48] = R.O03[3];
        pr = pout + 4096;           pr[0] = R.O10[0]; pr[16] = R.O11[0]; pr[32] = R.O12[0]; pr[48] = R.O13[0];
        pr = pout + 4096 + 256;     pr[0] = R.O10[1]; pr[16] = R.O11[1]; pr[32] = R.O12[1]; pr[48] = R.O13[1];
        pr = pout + 4096 + 512;     pr[0] = R.O10[2]; pr[16] = R.O11[2]; pr[32] = R.O12[2]; pr[48] = R.O13[2];
        pr = pout + 4096 + 768;     pr[0] = R.O10[3]; pr[16] = R.O11[3]; pr[32] = R.O12[3]; pr[48] = R.O13[3];
    }
}

// ---------- kernel 3: fused [reduce | final loss] ----------
// blocks 0..511: split-partial reduce + bias.  block 512: loss scalar
// (reads imp_p/cm_p written by the PREVIOUS launch — kernel-boundary
// ordering, no fences needed).
__global__ __launch_bounds__(256) void reduce_final_kernel(
    const float* __restrict__ partial, const float* __restrict__ bias,
    float* __restrict__ out, const float* __restrict__ imp_p,
    const float* __restrict__ cm_p, float* __restrict__ loss_out)
{
    const int t = threadIdx.x;

    if (blockIdx.x < 512) {
        int idx = blockIdx.x * 256 + t;   // float4 id, < 131072
        float4 s = ((const float4*)bias)[idx & 63];
        #pragma unroll
        for (int g = 0; g < 8; ++g) {
            float4 v = ((const float4*)partial)[((size_t)g << 17) + idx];
            s.x += v.x; s.y += v.y; s.z += v.z; s.w += v.w;
        }
        ((float4*)out)[idx] = s;
        return;
    }

    // ---- final loss (block 512, first wave) ----
    if (t < 64) {
        float imp = 0.f;
        #pragma unroll
        for (int b = 0; b < 32; ++b) imp += imp_p[(b << 6) + t];
        float ct = (t < 32) ? cm_p[t] : 0.f;
        ct = wave_sum(ct);
        float tot  = wave_sum(imp);
        float mean = tot * (1.0f / 64.f);
        float dv   = imp - mean;
        float var  = wave_sum(dv * dv) * (1.0f / 63.f);
        if (t == 0) {
            float mse = ct * (1.0f / (float)(NTOK * RD));
            float imp_loss = sqrtf(var) / mean;
            // commitment and kmeans losses are numerically identical forward
            loss_out[0] = (0.25f + 1.0f) * mse + 30.0f * imp_loss;
        }
    }
}

extern "C" void kernel_launch(void* const* d_in, const int* in_sizes, int n_in,
                              void* d_out, int out_size, void* d_ws, size_t ws_size,
                              hipStream_t stream)
{
    const float* x     = (const float*)d_in[0];
    const float* map_w = (const float*)d_in[1];
    const float* map_b = (const float*)d_in[2];
    const float* cent  = (const float*)d_in[3];
    const float* pw_w  = (const float*)d_in[4];
    const float* pw_B  = (const float*)d_in[5];
    float* out = (float*)d_out;

    char* ws = (char*)d_ws;
    float* resp        = (float*)ws;                          // 512 KB
    float* commit      = (float*)(ws + 524288);               // 8 KB
    float* imp_p       = (float*)(ws + 540672);               // 8 KB
    float* cm_p        = (float*)(ws + 557056);               // 128 B
    unsigned short* Bp = (unsigned short*)(ws + (1u << 20));  // 8 MB packed B
    float* partial     = (float*)(ws + (10u << 20));          // 8 * 2 MB = 16 MB

    vq_pack_kernel<<<2560, 256, 0, stream>>>(pw_w, Bp, x, map_w, map_b, cent,
                                             resp, commit);
    gemm_loss_kernel<<<544, 256, 0, stream>>>(x, resp, Bp, partial,
                                              commit, imp_p, cm_p);
    reduce_final_kernel<<<513, 256, 0, stream>>>(partial, pw_B, out,
                                                 imp_p, cm_p, out + NTOK * COUT);
}